// Round 18
// baseline (30.032 us; speedup 1.0000x reference)
//
#include <hip/hip_runtime.h>

// Problem constants
#define NB 8
#define CH 64
#define KP 8            // K = C/8
#define HWP 4096        // H*W
#define NHW (NB * HWP)  // 32768
#define PTILE 32        // p-rows per attn block

typedef float f32x16 __attribute__((ext_vector_type(16)));
typedef __bf16 bf16x8 __attribute__((ext_vector_type(8)));
typedef short short8v __attribute__((ext_vector_type(8)));

// Workspace layout (float offsets)
#define WS_FB  0                 // f bf16 [NB][HWP][8], pre-scaled by log2(e)
#define WS_GB  (NHW * 4)         // g bf16 [NB][HWP][8]
#define WS_SB  (NHW * 8)         // s bf16 [NB][HWP], pre-shuffled per 16

// s shuffle: within each 16-block, position j holds s[porder[j]],
// porder = {0,1,2,3, 8,9,10,11, 4,5,6,7, 12,13,14,15} (involution).
// Makes PV MFMA A-frag k-order match the e-tile C-reg q-order (verified R6-R17).
__device__ __forceinline__ int s_shuf_idx(int i) {
    return i ^ (((((i >> 2) ^ (i >> 3)) & 1) != 0) ? 12 : 0);
}

// ---------------------------------------------------------------------------
// Kernel 1: 1x1-conv projections — R16 8-way channel split (4 waves/SIMD).
// ---------------------------------------------------------------------------
__global__ __launch_bounds__(512) void proj_kernel(
    const float* __restrict__ x,
    const float* __restrict__ Wf, const float* __restrict__ bf,
    const float* __restrict__ Wg, const float* __restrict__ bg,
    const float* __restrict__ Ws, const float* __restrict__ bs,
    float* __restrict__ ws)
{
    __shared__ float part[7][64][17];     // 30.3 KB

    const int blk = blockIdx.x;           // 512 blocks: 64 per batch
    const int n   = blk >> 6;
    const int p0  = (blk & 63) << 6;      // 64 pixels per block
    const int px  = threadIdx.x & 63;
    const int q   = threadIdx.x >> 6;     // c-slice 0..7 (wave-uniform)
    const int p   = p0 + px;

    const float* xp = x + (size_t)n * CH * HWP + (size_t)(q * 8) * HWP + p;

    float accf[KP], accg[KP], accs;
    if (q == 0) {
#pragma unroll
        for (int k = 0; k < KP; ++k) { accf[k] = bf[k]; accg[k] = bg[k]; }
        accs = bs[0];
    } else {
#pragma unroll
        for (int k = 0; k < KP; ++k) { accf[k] = 0.f; accg[k] = 0.f; }
        accs = 0.f;
    }

#pragma unroll
    for (int c = 0; c < 8; ++c) {         // 8 independent coalesced loads
        float xv = xp[(size_t)c * HWP];
        int cc = q * 8 + c;
#pragma unroll
        for (int k = 0; k < KP; ++k) {
            accf[k] = fmaf(Wf[k * CH + cc], xv, accf[k]);
            accg[k] = fmaf(Wg[k * CH + cc], xv, accg[k]);
        }
        accs = fmaf(Ws[cc], xv, accs);
    }

    if (q != 0) {
        float* dst = part[q - 1][px];
#pragma unroll
        for (int k = 0; k < KP; ++k) { dst[k] = accf[k]; dst[KP + k] = accg[k]; }
        dst[16] = accs;
    }
    __syncthreads();

    if (q == 0) {
#pragma unroll
        for (int j = 0; j < 7; ++j) {
            const float* src = part[j][px];
#pragma unroll
            for (int k = 0; k < KP; ++k) { accf[k] += src[k]; accg[k] += src[KP + k]; }
            accs += src[16];
        }

        const float L2E = 1.4426950408889634f;
        bf16x8 fv, gv;
#pragma unroll
        for (int k = 0; k < KP; ++k) {
            fv[k] = (__bf16)(accf[k] * L2E);
            gv[k] = (__bf16)accg[k];
        }

        ushort* fb = (ushort*)(ws + WS_FB) + (size_t)(n * HWP + p) * 8;
        ushort* gb = (ushort*)(ws + WS_GB) + (size_t)(n * HWP + p) * 8;
        *(short8v*)fb = __builtin_bit_cast(short8v, fv);
        *(short8v*)gb = __builtin_bit_cast(short8v, gv);

        __bf16 sb16 = (__bf16)accs;
        ((ushort*)(ws + WS_SB))[(size_t)n * HWP + (p & ~15) + s_shuf_idx(p & 15)] =
            __builtin_bit_cast(ushort, sb16);
    }
}

// ---------------------------------------------------------------------------
// Kernel 2 (fused attn + merge + epilogue). R18: dual-pipe exp — half 1
// (c[0..7]) exact v_exp_f32 on the trans pipe; half 2 (c[8..15]) Schraudolph
// bf16-bit construction on the VALU pipe (score is log2-domain, so
// bf16(2^c) bits ~ (int)fma(c,128,16250.92); +-4% rel err, cancels in the
// softmax ratio). Per-tile trans cost halves (128->64cy); VALU +24cy; both
// pipes run concurrently across waves. Structure otherwise R15/R17.
// ---------------------------------------------------------------------------
__global__ __launch_bounds__(512, 8) void attn_finish_kernel(
    const float* __restrict__ x, const float* __restrict__ gamma,
    float* __restrict__ ws, float* __restrict__ out)
{
    __shared__ alignas(16) ushort s_lds[HWP];   // 8 KB: whole shuffled s row
    __shared__ ushort ones_lds[32];             // 64 B
    __shared__ float  part_l[8][PTILE];         // 1 KB
    __shared__ float  part_a[8][PTILE];         // 1 KB
    __shared__ float  att_lds[PTILE];           // 128 B

    const int blk  = blockIdx.x;       // 1024 = n(8) * ptile(128)
    const int n    = blk >> 7;
    const int p0   = (blk & 127) << 5;
    const int tid  = threadIdx.x;
    const int lane = tid & 63;
    const int w    = tid >> 6;         // 0..7 = q-split (512 q each)
    const int l31  = lane & 31;
    const int hi   = lane >> 5;

    // stage whole s row (4096 bf16 = 512 float4s = 1/thread) + ones
    ((float4*)s_lds)[tid] =
        ((const float4*)((const ushort*)(ws + WS_SB) + (size_t)n * HWP))[tid];
    if (tid < 16) ((uint*)ones_lds)[tid] = 0x3F803F80u;

    // B-fragment: f rows for this block's 32 p (lanes 0-31 real)
    const ushort* fbase = (const ushort*)(ws + WS_FB) + (size_t)n * HWP * KP;
    short8v z8 = {0, 0, 0, 0, 0, 0, 0, 0};
    bf16x8 bfrag = __builtin_bit_cast(bf16x8,
        hi ? z8 : *(const short8v*)(fbase + (size_t)(p0 + l31) * KP));

    const ushort* gbase = (const ushort*)(ws + WS_GB) + (size_t)n * HWP * KP;

    __syncthreads();    // s_lds ready — last barrier until merge

    f32x16 c_pv = {0.f};

    const int qw = w << 9;             // wave's q range start (512 q)
    // prefetch tile 0's g row (lanes 0-31; hi lanes use zero frag)
    short8v araw = z8;
    if (!hi) araw = *(const short8v*)(gbase + (size_t)(qw + l31) * KP);

#pragma unroll 1
    for (int t = 0; t < 16; ++t) {     // 16 tiles of 32 q
        bf16x8 afrag = __builtin_bit_cast(bf16x8, araw);
        // prefetch next tile's g row (L2-hit, hides under exp work)
        if (t + 1 < 16 && !hi)
            araw = *(const short8v*)(gbase + (size_t)(qw + (t + 1) * 32 + l31) * KP);

        const f32x16 czero = {0.f};
        f32x16 c = __builtin_amdgcn_mfma_f32_32x32x16_bf16(
            afrag, bfrag, czero, 0, 0, 0);

        const int qbase = qw + (t << 5);
        const ushort* ap = (l31 == 1) ? ones_lds : (s_lds + qbase + (hi << 3));

        // half 1: exact exp2 on trans pipe, cvt to bf16, PV MFMA
        {
#pragma unroll
            for (int r = 0; r < 8; ++r) c[r] = __builtin_amdgcn_exp2f(c[r]);
            bf16x8 elo;
#pragma unroll
            for (int r = 0; r < 8; ++r) elo[r] = (__bf16)c[r];
            bf16x8 a1 = __builtin_bit_cast(bf16x8, *(const short8v*)ap);
            c_pv = __builtin_amdgcn_mfma_f32_32x32x16_bf16(a1, elo, c_pv, 0, 0, 0);
        }
        // half 2: Schraudolph bf16(2^c) bit construction on the VALU pipe
        {
            uint pk0, pk1, pk2, pk3;
            {
                int i0 = (int)fmaf(c[8],  128.f, 16250.92f);
                int i1 = (int)fmaf(c[9],  128.f, 16250.92f);
                pk0 = (uint)(i1 << 16) | (uint)i0;
                int i2 = (int)fmaf(c[10], 128.f, 16250.92f);
                int i3 = (int)fmaf(c[11], 128.f, 16250.92f);
                pk1 = (uint)(i3 << 16) | (uint)i2;
                int i4 = (int)fmaf(c[12], 128.f, 16250.92f);
                int i5 = (int)fmaf(c[13], 128.f, 16250.92f);
                pk2 = (uint)(i5 << 16) | (uint)i4;
                int i6 = (int)fmaf(c[14], 128.f, 16250.92f);
                int i7 = (int)fmaf(c[15], 128.f, 16250.92f);
                pk3 = (uint)(i7 << 16) | (uint)i6;
            }
            uint4 pku = make_uint4(pk0, pk1, pk2, pk3);
            bf16x8 ehi = __builtin_bit_cast(bf16x8, pku);
            bf16x8 a2 = __builtin_bit_cast(bf16x8, *(const short8v*)(ap + 16));
            c_pv = __builtin_amdgcn_mfma_f32_32x32x16_bf16(a2, ehi, c_pv, 0, 0, 0);
        }
    }

    // partials: D rows 0 = sum e*s, 1 = sum e (regs 0,1 of hi=0 lanes)
    if (!hi) {
        part_a[w][l31] = c_pv[0];
        part_l[w][l31] = c_pv[1];
    }
    __syncthreads();

    // merge + att_map output
    if (tid < PTILE) {
        float l = 0.f, a = 0.f;
#pragma unroll
        for (int j = 0; j < 8; ++j) { l += part_l[j][tid]; a += part_a[j][tid]; }
        float att = a / l;
        att_lds[tid] = att;
        out[(size_t)n * HWP + p0 + tid] = att;
    }
    __syncthreads();

    // epilogue: out = att*gamma + x (x is L2/L3-resident)
    const float gm = gamma[0];
    const float* xn = x + (size_t)n * CH * HWP + p0;
    float* outp = out + NHW + (size_t)n * CH * HWP + p0;
    {
        int c  = tid >> 3;             // 512 float4s over (c, p/4), 1/thread
        int p4 = (tid & 7) << 2;
        float4 xv = *(const float4*)(xn + (size_t)c * HWP + p4);
        float4 av = *(const float4*)(att_lds + p4);
        float4 o;
        o.x = fmaf(av.x, gm, xv.x);
        o.y = fmaf(av.y, gm, xv.y);
        o.z = fmaf(av.z, gm, xv.z);
        o.w = fmaf(av.w, gm, xv.w);
        *(float4*)(outp + (size_t)c * HWP + p4) = o;
    }
}

extern "C" void kernel_launch(void* const* d_in, const int* in_sizes, int n_in,
                              void* d_out, int out_size, void* d_ws, size_t ws_size,
                              hipStream_t stream) {
    const float* x     = (const float*)d_in[0];
    const float* Wf    = (const float*)d_in[1];
    const float* bf    = (const float*)d_in[2];
    const float* Wg    = (const float*)d_in[3];
    const float* bg    = (const float*)d_in[4];
    const float* Ws    = (const float*)d_in[5];
    const float* bs    = (const float*)d_in[6];
    const float* gamma = (const float*)d_in[7];
    float* out = (float*)d_out;
    float* ws  = (float*)d_ws;

    // d_out layout: att_map [NB*HWP] then output [NB*CH*HWP]
    proj_kernel<<<NB * (HWP / 64), 512, 0, stream>>>(x, Wf, bf, Wg, bg, Ws, bs, ws);
    attn_finish_kernel<<<NB * (HWP / PTILE), 512, 0, stream>>>(x, gamma, ws, out);
}

// Round 19
// 29.083 us; speedup vs baseline: 1.0326x; 1.0326x over previous
//
#include <hip/hip_runtime.h>

// Problem constants
#define NB 8
#define CH 64
#define KP 8            // K = C/8
#define HWP 4096        // H*W
#define NHW (NB * HWP)  // 32768
#define PTILE 32        // p-rows per attn block

typedef float f32x16 __attribute__((ext_vector_type(16)));
typedef __bf16 bf16x8 __attribute__((ext_vector_type(8)));
typedef short short8v __attribute__((ext_vector_type(8)));

// Workspace layout (float offsets)
#define WS_FB  0                 // f bf16 [NB][HWP][8], pre-scaled by log2(e)
#define WS_GB  (NHW * 4)         // g bf16 [NB][HWP][8]
#define WS_SB  (NHW * 8)         // s bf16 [NB][HWP], pre-shuffled per 16

// s shuffle: within each 16-block, position j holds s[porder[j]],
// porder = {0,1,2,3, 8,9,10,11, 4,5,6,7, 12,13,14,15} (involution).
// Makes PV MFMA A-frag k-order match the e-tile C-reg q-order (verified R6-R18).
__device__ __forceinline__ int s_shuf_idx(int i) {
    return i ^ (((((i >> 2) ^ (i >> 3)) & 1) != 0) ? 12 : 0);
}

// ---------------------------------------------------------------------------
// Kernel 1: 1x1-conv projections — R16 8-way channel split (4 waves/SIMD).
// ---------------------------------------------------------------------------
__global__ __launch_bounds__(512) void proj_kernel(
    const float* __restrict__ x,
    const float* __restrict__ Wf, const float* __restrict__ bf,
    const float* __restrict__ Wg, const float* __restrict__ bg,
    const float* __restrict__ Ws, const float* __restrict__ bs,
    float* __restrict__ ws)
{
    __shared__ float part[7][64][17];     // 30.3 KB

    const int blk = blockIdx.x;           // 512 blocks: 64 per batch
    const int n   = blk >> 6;
    const int p0  = (blk & 63) << 6;      // 64 pixels per block
    const int px  = threadIdx.x & 63;
    const int q   = threadIdx.x >> 6;     // c-slice 0..7 (wave-uniform)
    const int p   = p0 + px;

    const float* xp = x + (size_t)n * CH * HWP + (size_t)(q * 8) * HWP + p;

    float accf[KP], accg[KP], accs;
    if (q == 0) {
#pragma unroll
        for (int k = 0; k < KP; ++k) { accf[k] = bf[k]; accg[k] = bg[k]; }
        accs = bs[0];
    } else {
#pragma unroll
        for (int k = 0; k < KP; ++k) { accf[k] = 0.f; accg[k] = 0.f; }
        accs = 0.f;
    }

#pragma unroll
    for (int c = 0; c < 8; ++c) {         // 8 independent coalesced loads
        float xv = xp[(size_t)c * HWP];
        int cc = q * 8 + c;
#pragma unroll
        for (int k = 0; k < KP; ++k) {
            accf[k] = fmaf(Wf[k * CH + cc], xv, accf[k]);
            accg[k] = fmaf(Wg[k * CH + cc], xv, accg[k]);
        }
        accs = fmaf(Ws[cc], xv, accs);
    }

    if (q != 0) {
        float* dst = part[q - 1][px];
#pragma unroll
        for (int k = 0; k < KP; ++k) { dst[k] = accf[k]; dst[KP + k] = accg[k]; }
        dst[16] = accs;
    }
    __syncthreads();

    if (q == 0) {
#pragma unroll
        for (int j = 0; j < 7; ++j) {
            const float* src = part[j][px];
#pragma unroll
            for (int k = 0; k < KP; ++k) { accf[k] += src[k]; accg[k] += src[KP + k]; }
            accs += src[16];
        }

        const float L2E = 1.4426950408889634f;
        bf16x8 fv, gv;
#pragma unroll
        for (int k = 0; k < KP; ++k) {
            fv[k] = (__bf16)(accf[k] * L2E);
            gv[k] = (__bf16)accg[k];
        }

        ushort* fb = (ushort*)(ws + WS_FB) + (size_t)(n * HWP + p) * 8;
        ushort* gb = (ushort*)(ws + WS_GB) + (size_t)(n * HWP + p) * 8;
        *(short8v*)fb = __builtin_bit_cast(short8v, fv);
        *(short8v*)gb = __builtin_bit_cast(short8v, gv);

        __bf16 sb16 = (__bf16)accs;
        ((ushort*)(ws + WS_SB))[(size_t)n * HWP + (p & ~15) + s_shuf_idx(p & 15)] =
            __builtin_bit_cast(ushort, sb16);
    }
}

// ---------------------------------------------------------------------------
// Kernel 2 (fused attn + merge + epilogue). R19: 2-tile software pipeline —
// tile pair (2t, 2t+1): both score MFMAs issue back-to-back; next pair's
// g-row loads issue under the exp/PV work; the two exp/PV streams feed
// INDEPENDENT accumulators c_pv0/c_pv1 (no cross-tile chaining), merged
// once at the end. (512,4): ILP replaces TLP; live ~100 VGPR, no spill.
// Per-tile math identical R6-R18.
// ---------------------------------------------------------------------------
__global__ __launch_bounds__(512, 4) void attn_finish_kernel(
    const float* __restrict__ x, const float* __restrict__ gamma,
    float* __restrict__ ws, float* __restrict__ out)
{
    __shared__ alignas(16) ushort s_lds[HWP];   // 8 KB: whole shuffled s row
    __shared__ ushort ones_lds[32];             // 64 B
    __shared__ float  part_l[8][PTILE];         // 1 KB
    __shared__ float  part_a[8][PTILE];         // 1 KB
    __shared__ float  att_lds[PTILE];           // 128 B

    const int blk  = blockIdx.x;       // 1024 = n(8) * ptile(128)
    const int n    = blk >> 7;
    const int p0   = (blk & 127) << 5;
    const int tid  = threadIdx.x;
    const int lane = tid & 63;
    const int w    = tid >> 6;         // 0..7 = q-split (512 q each)
    const int l31  = lane & 31;
    const int hi   = lane >> 5;

    // stage whole s row (4096 bf16 = 512 float4s = 1/thread) + ones
    ((float4*)s_lds)[tid] =
        ((const float4*)((const ushort*)(ws + WS_SB) + (size_t)n * HWP))[tid];
    if (tid < 16) ((uint*)ones_lds)[tid] = 0x3F803F80u;

    // B-fragment: f rows for this block's 32 p (lanes 0-31 real)
    const ushort* fbase = (const ushort*)(ws + WS_FB) + (size_t)n * HWP * KP;
    short8v z8 = {0, 0, 0, 0, 0, 0, 0, 0};
    bf16x8 bfrag = __builtin_bit_cast(bf16x8,
        hi ? z8 : *(const short8v*)(fbase + (size_t)(p0 + l31) * KP));

    const ushort* gbase = (const ushort*)(ws + WS_GB) + (size_t)n * HWP * KP;

    __syncthreads();    // s_lds ready — last barrier until merge

    f32x16 c_pv0 = {0.f};
    f32x16 c_pv1 = {0.f};

    const int qw = w << 9;             // wave's q range start (512 q)
    // preload pair 0's two g rows (lanes 0-31; hi lanes use zero frag)
    short8v araw0 = z8, araw1 = z8;
    if (!hi) {
        araw0 = *(const short8v*)(gbase + (size_t)(qw + l31) * KP);
        araw1 = *(const short8v*)(gbase + (size_t)(qw + 32 + l31) * KP);
    }

#pragma unroll 1
    for (int tp = 0; tp < 8; ++tp) {   // 8 pairs of 32-q tiles
        bf16x8 af0 = __builtin_bit_cast(bf16x8, araw0);
        bf16x8 af1 = __builtin_bit_cast(bf16x8, araw1);

        const f32x16 czero = {0.f};
        // both score MFMAs issue back-to-back (independent)
        f32x16 c0 = __builtin_amdgcn_mfma_f32_32x32x16_bf16(af0, bfrag, czero, 0, 0, 0);
        f32x16 c1 = __builtin_amdgcn_mfma_f32_32x32x16_bf16(af1, bfrag, czero, 0, 0, 0);

        // prefetch next pair's g rows — latency covered by exp/PV below
        if (tp + 1 < 8 && !hi) {
            araw0 = *(const short8v*)(gbase + (size_t)(qw + (tp * 2 + 2) * 32 + l31) * KP);
            araw1 = *(const short8v*)(gbase + (size_t)(qw + (tp * 2 + 3) * 32 + l31) * KP);
        }

        const int qb0 = qw + (tp << 6);
        const ushort* ap0 = (l31 == 1) ? ones_lds : (s_lds + qb0 + (hi << 3));
        const ushort* ap1 = (l31 == 1) ? ones_lds : (s_lds + qb0 + 32 + (hi << 3));

        // tile 2tp   -> c_pv0
#pragma unroll
        for (int r = 0; r < 16; ++r) c0[r] = __builtin_amdgcn_exp2f(c0[r]);
        {
            bf16x8 elo, ehi;
#pragma unroll
            for (int r = 0; r < 8; ++r) { elo[r] = (__bf16)c0[r]; ehi[r] = (__bf16)c0[r + 8]; }
            bf16x8 a1 = __builtin_bit_cast(bf16x8, *(const short8v*)ap0);
            bf16x8 a2 = __builtin_bit_cast(bf16x8, *(const short8v*)(ap0 + 16));
            c_pv0 = __builtin_amdgcn_mfma_f32_32x32x16_bf16(a1, elo, c_pv0, 0, 0, 0);
            c_pv0 = __builtin_amdgcn_mfma_f32_32x32x16_bf16(a2, ehi, c_pv0, 0, 0, 0);
        }
        // tile 2tp+1 -> c_pv1 (independent stream)
#pragma unroll
        for (int r = 0; r < 16; ++r) c1[r] = __builtin_amdgcn_exp2f(c1[r]);
        {
            bf16x8 elo, ehi;
#pragma unroll
            for (int r = 0; r < 8; ++r) { elo[r] = (__bf16)c1[r]; ehi[r] = (__bf16)c1[r + 8]; }
            bf16x8 a1 = __builtin_bit_cast(bf16x8, *(const short8v*)ap1);
            bf16x8 a2 = __builtin_bit_cast(bf16x8, *(const short8v*)(ap1 + 16));
            c_pv1 = __builtin_amdgcn_mfma_f32_32x32x16_bf16(a1, elo, c_pv1, 0, 0, 0);
            c_pv1 = __builtin_amdgcn_mfma_f32_32x32x16_bf16(a2, ehi, c_pv1, 0, 0, 0);
        }
    }

    // partials: D rows 0 = sum e*s, 1 = sum e (regs 0,1 of hi=0 lanes)
    if (!hi) {
        part_a[w][l31] = c_pv0[0] + c_pv1[0];
        part_l[w][l31] = c_pv0[1] + c_pv1[1];
    }
    __syncthreads();

    // merge + att_map output
    if (tid < PTILE) {
        float l = 0.f, a = 0.f;
#pragma unroll
        for (int j = 0; j < 8; ++j) { l += part_l[j][tid]; a += part_a[j][tid]; }
        float att = a / l;
        att_lds[tid] = att;
        out[(size_t)n * HWP + p0 + tid] = att;
    }
    __syncthreads();

    // epilogue: out = att*gamma + x (x is L2/L3-resident)
    const float gm = gamma[0];
    const float* xn = x + (size_t)n * CH * HWP + p0;
    float* outp = out + NHW + (size_t)n * CH * HWP + p0;
    {
        int c  = tid >> 3;             // 512 float4s over (c, p/4), 1/thread
        int p4 = (tid & 7) << 2;
        float4 xv = *(const float4*)(xn + (size_t)c * HWP + p4);
        float4 av = *(const float4*)(att_lds + p4);
        float4 o;
        o.x = fmaf(av.x, gm, xv.x);
        o.y = fmaf(av.y, gm, xv.y);
        o.z = fmaf(av.z, gm, xv.z);
        o.w = fmaf(av.w, gm, xv.w);
        *(float4*)(outp + (size_t)c * HWP + p4) = o;
    }
}

extern "C" void kernel_launch(void* const* d_in, const int* in_sizes, int n_in,
                              void* d_out, int out_size, void* d_ws, size_t ws_size,
                              hipStream_t stream) {
    const float* x     = (const float*)d_in[0];
    const float* Wf    = (const float*)d_in[1];
    const float* bf    = (const float*)d_in[2];
    const float* Wg    = (const float*)d_in[3];
    const float* bg    = (const float*)d_in[4];
    const float* Ws    = (const float*)d_in[5];
    const float* bs    = (const float*)d_in[6];
    const float* gamma = (const float*)d_in[7];
    float* out = (float*)d_out;
    float* ws  = (float*)d_ws;

    // d_out layout: att_map [NB*HWP] then output [NB*CH*HWP]
    proj_kernel<<<NB * (HWP / 64), 512, 0, stream>>>(x, Wf, bf, Wg, bg, Ws, bs, ws);
    attn_finish_kernel<<<NB * (HWP / PTILE), 512, 0, stream>>>(x, gamma, ws, out);
}

// Round 20
// 28.892 us; speedup vs baseline: 1.0395x; 1.0066x over previous
//
#include <hip/hip_runtime.h>

// Problem constants
#define NB 8
#define CH 64
#define KP 8            // K = C/8
#define HWP 4096        // H*W
#define NHW (NB * HWP)  // 32768
#define PTILE 32        // p-rows per attn block

typedef float f32x16 __attribute__((ext_vector_type(16)));
typedef __bf16 bf16x8 __attribute__((ext_vector_type(8)));
typedef short short8v __attribute__((ext_vector_type(8)));

// Workspace layout (float offsets)
#define WS_FB  0                 // f bf16 [NB][HWP][8], pre-scaled by log2(e)
#define WS_GB  (NHW * 4)         // g bf16 [NB][HWP][8]
#define WS_SB  (NHW * 8)         // s bf16 [NB][HWP], pre-shuffled per 16

// s shuffle: within each 16-block, position j holds s[porder[j]],
// porder = {0,1,2,3, 8,9,10,11, 4,5,6,7, 12,13,14,15} (involution).
// Makes PV MFMA A-frag k-order match the e-tile C-reg q-order (verified R6-R19).
__device__ __forceinline__ int s_shuf_idx(int i) {
    return i ^ (((((i >> 2) ^ (i >> 3)) & 1) != 0) ? 12 : 0);
}

// ---------------------------------------------------------------------------
// Kernel 1: 1x1-conv projections — R16 8-way channel split (4 waves/SIMD).
// ---------------------------------------------------------------------------
__global__ __launch_bounds__(512) void proj_kernel(
    const float* __restrict__ x,
    const float* __restrict__ Wf, const float* __restrict__ bf,
    const float* __restrict__ Wg, const float* __restrict__ bg,
    const float* __restrict__ Ws, const float* __restrict__ bs,
    float* __restrict__ ws)
{
    __shared__ float part[7][64][17];     // 30.3 KB

    const int blk = blockIdx.x;           // 512 blocks: 64 per batch
    const int n   = blk >> 6;
    const int p0  = (blk & 63) << 6;      // 64 pixels per block
    const int px  = threadIdx.x & 63;
    const int q   = threadIdx.x >> 6;     // c-slice 0..7 (wave-uniform)
    const int p   = p0 + px;

    const float* xp = x + (size_t)n * CH * HWP + (size_t)(q * 8) * HWP + p;

    float accf[KP], accg[KP], accs;
    if (q == 0) {
#pragma unroll
        for (int k = 0; k < KP; ++k) { accf[k] = bf[k]; accg[k] = bg[k]; }
        accs = bs[0];
    } else {
#pragma unroll
        for (int k = 0; k < KP; ++k) { accf[k] = 0.f; accg[k] = 0.f; }
        accs = 0.f;
    }

#pragma unroll
    for (int c = 0; c < 8; ++c) {         // 8 independent coalesced loads
        float xv = xp[(size_t)c * HWP];
        int cc = q * 8 + c;
#pragma unroll
        for (int k = 0; k < KP; ++k) {
            accf[k] = fmaf(Wf[k * CH + cc], xv, accf[k]);
            accg[k] = fmaf(Wg[k * CH + cc], xv, accg[k]);
        }
        accs = fmaf(Ws[cc], xv, accs);
    }

    if (q != 0) {
        float* dst = part[q - 1][px];
#pragma unroll
        for (int k = 0; k < KP; ++k) { dst[k] = accf[k]; dst[KP + k] = accg[k]; }
        dst[16] = accs;
    }
    __syncthreads();

    if (q == 0) {
#pragma unroll
        for (int j = 0; j < 7; ++j) {
            const float* src = part[j][px];
#pragma unroll
            for (int k = 0; k < KP; ++k) { accf[k] += src[k]; accg[k] += src[KP + k]; }
            accs += src[16];
        }

        const float L2E = 1.4426950408889634f;
        bf16x8 fv, gv;
#pragma unroll
        for (int k = 0; k < KP; ++k) {
            fv[k] = (__bf16)(accf[k] * L2E);
            gv[k] = (__bf16)accg[k];
        }

        ushort* fb = (ushort*)(ws + WS_FB) + (size_t)(n * HWP + p) * 8;
        ushort* gb = (ushort*)(ws + WS_GB) + (size_t)(n * HWP + p) * 8;
        *(short8v*)fb = __builtin_bit_cast(short8v, fv);
        *(short8v*)gb = __builtin_bit_cast(short8v, gv);

        __bf16 sb16 = (__bf16)accs;
        ((ushort*)(ws + WS_SB))[(size_t)n * HWP + (p & ~15) + s_shuf_idx(p & 15)] =
            __builtin_bit_cast(ushort, sb16);
    }
}

// ---------------------------------------------------------------------------
// Kernel 2 (fused attn + merge + epilogue). R20 = R19 + s_setprio(1) around
// the MFMA/exp cluster (T5: helps when co-resident waves are at different
// phases — our barrier-free waves drift). Structure: 2-tile pipeline,
// independent c_pv0/c_pv1, barrier-free sweep, g from L2, s staged once.
// Per-tile math identical R6-R19 (absmax 0.015625).
// ---------------------------------------------------------------------------
__global__ __launch_bounds__(512, 4) void attn_finish_kernel(
    const float* __restrict__ x, const float* __restrict__ gamma,
    float* __restrict__ ws, float* __restrict__ out)
{
    __shared__ alignas(16) ushort s_lds[HWP];   // 8 KB: whole shuffled s row
    __shared__ ushort ones_lds[32];             // 64 B
    __shared__ float  part_l[8][PTILE];         // 1 KB
    __shared__ float  part_a[8][PTILE];         // 1 KB
    __shared__ float  att_lds[PTILE];           // 128 B

    const int blk  = blockIdx.x;       // 1024 = n(8) * ptile(128)
    const int n    = blk >> 7;
    const int p0   = (blk & 127) << 5;
    const int tid  = threadIdx.x;
    const int lane = tid & 63;
    const int w    = tid >> 6;         // 0..7 = q-split (512 q each)
    const int l31  = lane & 31;
    const int hi   = lane >> 5;

    // stage whole s row (4096 bf16 = 512 float4s = 1/thread) + ones
    ((float4*)s_lds)[tid] =
        ((const float4*)((const ushort*)(ws + WS_SB) + (size_t)n * HWP))[tid];
    if (tid < 16) ((uint*)ones_lds)[tid] = 0x3F803F80u;

    // B-fragment: f rows for this block's 32 p (lanes 0-31 real)
    const ushort* fbase = (const ushort*)(ws + WS_FB) + (size_t)n * HWP * KP;
    short8v z8 = {0, 0, 0, 0, 0, 0, 0, 0};
    bf16x8 bfrag = __builtin_bit_cast(bf16x8,
        hi ? z8 : *(const short8v*)(fbase + (size_t)(p0 + l31) * KP));

    const ushort* gbase = (const ushort*)(ws + WS_GB) + (size_t)n * HWP * KP;

    __syncthreads();    // s_lds ready — last barrier until merge

    f32x16 c_pv0 = {0.f};
    f32x16 c_pv1 = {0.f};

    const int qw = w << 9;             // wave's q range start (512 q)
    // preload pair 0's two g rows (lanes 0-31; hi lanes use zero frag)
    short8v araw0 = z8, araw1 = z8;
    if (!hi) {
        araw0 = *(const short8v*)(gbase + (size_t)(qw + l31) * KP);
        araw1 = *(const short8v*)(gbase + (size_t)(qw + 32 + l31) * KP);
    }

#pragma unroll 1
    for (int tp = 0; tp < 8; ++tp) {   // 8 pairs of 32-q tiles
        bf16x8 af0 = __builtin_bit_cast(bf16x8, araw0);
        bf16x8 af1 = __builtin_bit_cast(bf16x8, araw1);

        const f32x16 czero = {0.f};
        __builtin_amdgcn_s_setprio(1);
        // both score MFMAs issue back-to-back (independent)
        f32x16 c0 = __builtin_amdgcn_mfma_f32_32x32x16_bf16(af0, bfrag, czero, 0, 0, 0);
        f32x16 c1 = __builtin_amdgcn_mfma_f32_32x32x16_bf16(af1, bfrag, czero, 0, 0, 0);
        __builtin_amdgcn_s_setprio(0);

        // prefetch next pair's g rows — latency covered by exp/PV below
        if (tp + 1 < 8 && !hi) {
            araw0 = *(const short8v*)(gbase + (size_t)(qw + (tp * 2 + 2) * 32 + l31) * KP);
            araw1 = *(const short8v*)(gbase + (size_t)(qw + (tp * 2 + 3) * 32 + l31) * KP);
        }

        const int qb0 = qw + (tp << 6);
        const ushort* ap0 = (l31 == 1) ? ones_lds : (s_lds + qb0 + (hi << 3));
        const ushort* ap1 = (l31 == 1) ? ones_lds : (s_lds + qb0 + 32 + (hi << 3));

        // tile 2tp   -> c_pv0
#pragma unroll
        for (int r = 0; r < 16; ++r) c0[r] = __builtin_amdgcn_exp2f(c0[r]);
        {
            bf16x8 elo, ehi;
#pragma unroll
            for (int r = 0; r < 8; ++r) { elo[r] = (__bf16)c0[r]; ehi[r] = (__bf16)c0[r + 8]; }
            bf16x8 a1 = __builtin_bit_cast(bf16x8, *(const short8v*)ap0);
            bf16x8 a2 = __builtin_bit_cast(bf16x8, *(const short8v*)(ap0 + 16));
            __builtin_amdgcn_s_setprio(1);
            c_pv0 = __builtin_amdgcn_mfma_f32_32x32x16_bf16(a1, elo, c_pv0, 0, 0, 0);
            c_pv0 = __builtin_amdgcn_mfma_f32_32x32x16_bf16(a2, ehi, c_pv0, 0, 0, 0);
            __builtin_amdgcn_s_setprio(0);
        }
        // tile 2tp+1 -> c_pv1 (independent stream)
#pragma unroll
        for (int r = 0; r < 16; ++r) c1[r] = __builtin_amdgcn_exp2f(c1[r]);
        {
            bf16x8 elo, ehi;
#pragma unroll
            for (int r = 0; r < 8; ++r) { elo[r] = (__bf16)c1[r]; ehi[r] = (__bf16)c1[r + 8]; }
            bf16x8 a1 = __builtin_bit_cast(bf16x8, *(const short8v*)ap1);
            bf16x8 a2 = __builtin_bit_cast(bf16x8, *(const short8v*)(ap1 + 16));
            __builtin_amdgcn_s_setprio(1);
            c_pv1 = __builtin_amdgcn_mfma_f32_32x32x16_bf16(a1, elo, c_pv1, 0, 0, 0);
            c_pv1 = __builtin_amdgcn_mfma_f32_32x32x16_bf16(a2, ehi, c_pv1, 0, 0, 0);
            __builtin_amdgcn_s_setprio(0);
        }
    }

    // partials: D rows 0 = sum e*s, 1 = sum e (regs 0,1 of hi=0 lanes)
    if (!hi) {
        part_a[w][l31] = c_pv0[0] + c_pv1[0];
        part_l[w][l31] = c_pv0[1] + c_pv1[1];
    }
    __syncthreads();

    // merge + att_map output
    if (tid < PTILE) {
        float l = 0.f, a = 0.f;
#pragma unroll
        for (int j = 0; j < 8; ++j) { l += part_l[j][tid]; a += part_a[j][tid]; }
        float att = a / l;
        att_lds[tid] = att;
        out[(size_t)n * HWP + p0 + tid] = att;
    }
    __syncthreads();

    // epilogue: out = att*gamma + x (x is L2/L3-resident)
    const float gm = gamma[0];
    const float* xn = x + (size_t)n * CH * HWP + p0;
    float* outp = out + NHW + (size_t)n * CH * HWP + p0;
    {
        int c  = tid >> 3;             // 512 float4s over (c, p/4), 1/thread
        int p4 = (tid & 7) << 2;
        float4 xv = *(const float4*)(xn + (size_t)c * HWP + p4);
        float4 av = *(const float4*)(att_lds + p4);
        float4 o;
        o.x = fmaf(av.x, gm, xv.x);
        o.y = fmaf(av.y, gm, xv.y);
        o.z = fmaf(av.z, gm, xv.z);
        o.w = fmaf(av.w, gm, xv.w);
        *(float4*)(outp + (size_t)c * HWP + p4) = o;
    }
}

extern "C" void kernel_launch(void* const* d_in, const int* in_sizes, int n_in,
                              void* d_out, int out_size, void* d_ws, size_t ws_size,
                              hipStream_t stream) {
    const float* x     = (const float*)d_in[0];
    const float* Wf    = (const float*)d_in[1];
    const float* bf    = (const float*)d_in[2];
    const float* Wg    = (const float*)d_in[3];
    const float* bg    = (const float*)d_in[4];
    const float* Ws    = (const float*)d_in[5];
    const float* bs    = (const float*)d_in[6];
    const float* gamma = (const float*)d_in[7];
    float* out = (float*)d_out;
    float* ws  = (float*)d_ws;

    // d_out layout: att_map [NB*HWP] then output [NB*CH*HWP]
    proj_kernel<<<NB * (HWP / 64), 512, 0, stream>>>(x, Wf, bf, Wg, bg, Ws, bs, ws);
    attn_finish_kernel<<<NB * (HWP / PTILE), 512, 0, stream>>>(x, gamma, ws, out);
}